// Round 3
// baseline (573.363 us; speedup 1.0000x reference)
//
#include <hip/hip_runtime.h>

// VectorQuantizer on MI355X — replicate numpy-fp32 rounding in the distance,
// so argmin matches the np reference's grid-quantized distances exactly.
// x: (32,256,32,32) fp32, codebook: (1024,256) fp32.
// Outputs concat: quantized (8388608 f32), vq_loss (1 f32), indices (32768 as f32).
//
// v4: split the operand streams across pipes. v1-v3 fed BOTH z and e from
// LDS (z: 4096 + e: 4096 b128/thread) -> LDS-instruction-bound (~13cyc each,
// ~850K cyc/CU). x is [d][m]-contiguous in global, so z-reads are perfectly
// coalesced 256B broadcast VMEM transactions (L1/L2-resident tile) -> move z
// to the VMEM pipe, keep only e in LDS. LDS instrs halve; zT's 64KB of LDS
// and its staging vanish.
//  - 4m x 4k register tile (v1's, known to fit the 128-VGPR cap the
//    allocator enforces; v2/v3's 4x8 spilled ~330MB of scratch writes).
//  - eT [k][d] row-major, double-buffered 2x8KB. No transpose on staging.
//  - XOR swizzle: physical 16B block bq^((k>>2)&7) -> the 4-distinct-row
//    e-read is bank-conflict-free; applied via permuted global source
//    offset on store + XOR-folded row base on read.
//  - Prefetch next e-tile AFTER the 2nd barrier: the auto vmcnt-drain
//    before the next phase's barrier lands after a full compute phase.
//  - Per-output arithmetic bit-identical to v1 (d-ascending fp32 fma
//    chains of 32, double chunk-sum over dc, same epilogue rounding,
//    earliest-k tie-break).

#define NUM_K 1024
#define DIM   256
#define HW    1024          // H*W
#define N_TOT 32768         // B*H*W
#define TM    64            // n-tile per block
#define TK    64            // k-tile
#define DB    32            // d-chunk per phase (numpy chunk size)
#define NKT   (NUM_K / TK)  // 16
#define NDC   (DIM / DB)    // 8
#define NPH   (NKT * NDC)   // 128
#define LOSS_OFF 8388608
#define IDX_OFF  8388609

// numpy pairwise sum of squares over 256 elements, exact numpy order.
__device__ __forceinline__ float np_sumsq_256(const float* p, int stride) {
    float s[2];
    #pragma unroll
    for (int h = 0; h < 2; ++h) {
        const float* base = p + h * 128 * stride;
        float r[8];
        #pragma unroll
        for (int j = 0; j < 8; ++j) {
            float v = base[j * stride];
            r[j] = __fmul_rn(v, v);
        }
        for (int i = 8; i < 128; i += 8) {
            #pragma unroll
            for (int j = 0; j < 8; ++j) {
                float v = base[(i + j) * stride];
                r[j] = __fadd_rn(r[j], __fmul_rn(v, v));
            }
        }
        s[h] = __fadd_rn(__fadd_rn(__fadd_rn(r[0], r[1]), __fadd_rn(r[2], r[3])),
                         __fadd_rn(__fadd_rn(r[4], r[5]), __fadd_rn(r[6], r[7])));
    }
    return __fadd_rn(s[0], s[1]);
}

__global__ __launch_bounds__(256) void u2_kernel(const float* __restrict__ cb,
                                                 float* __restrict__ u2) {
    int k = blockIdx.x * 256 + threadIdx.x;     // 4 blocks x 256
    u2[k] = np_sumsq_256(cb + (size_t)k * DIM, 1);
}

__global__ __launch_bounds__(256) void vq_main(const float* __restrict__ x,
                                               const float* __restrict__ cb,
                                               const float* __restrict__ u2,
                                               float* __restrict__ out) {
    __shared__ __align__(16) float eT[2][TK * DB];   // 2 x 8 KB, [k][d] + swizzle
    __shared__ float red_v[4][TM];
    __shared__ int   red_k[4][TM];
    __shared__ int   bestk_s[TM];
    __shared__ float wsum[4];

    const int t  = threadIdx.x;
    const int g  = blockIdx.x;          // 512 blocks
    const int n0 = g * TM;
    const int b  = n0 >> 10;            // /1024
    const int r0 = n0 & (HW - 1);
    const size_t xbase = (size_t)b * (DIM * HW) + r0;

    // ---- staging map: 16B chunk cid -> LDS linear (row k=cid>>3, phys
    // block b'=cid&7); the value stored there is global block b'^((k>>2)&7)
    // of row k0+k, so a read at (row, bq^s) yields global quad bq. ----
    const int cid0 = t, cid1 = 256 + t;          // 2 chunks/thread, 512 total
    const int gof0 = (cid0 >> 3) * DIM + ((((cid0 & 7) ^ ((cid0 >> 5) & 7))) << 2);
    const int gof1 = (cid1 >> 3) * DIM + ((((cid1 & 7) ^ ((cid1 >> 5) & 7))) << 2);

    const int tm4 = (t & 15) * 4;       // 4 m's per thread
    const int tk4 = (t >> 4) * 4;       // 4 k's (within k-tile) per thread

    // swizzle-folded LDS row bases (float index): row*32 ^ (((row>>2)&7)<<2)
    const int sb0 = ((tk4 + 0) << 5) ^ ((((tk4 + 0) >> 2) & 7) << 2);
    const int sb1 = ((tk4 + 1) << 5) ^ ((((tk4 + 1) >> 2) & 7) << 2);
    const int sb2 = ((tk4 + 2) << 5) ^ ((((tk4 + 2) >> 2) & 7) << 2);
    const int sb3 = ((tk4 + 3) << 5) ^ ((((tk4 + 3) >> 2) & 7) << 2);

    // ---- numpy-order ||z||^2 straight from global x (coalesced per d) ----
    float myTs = np_sumsq_256(x + xbase + (t & 63), HW);
    float Tsr[4];
    #pragma unroll
    for (int i = 0; i < 4; ++i) Tsr[i] = __shfl(myTs, tm4 + i, 64);

    // ---- prologue: stage regs for phase 0 (k0=0, d0=0) ----
    float4 sA = *(const float4*)(cb + gof0);
    float4 sB = *(const float4*)(cb + gof1);

    float best_v[4] = {3.4e38f, 3.4e38f, 3.4e38f, 3.4e38f};
    int   best_k[4] = {0, 0, 0, 0};

    for (int kt = 0; kt < NKT; ++kt) {
        const int k0 = kt * TK;
        double accd[4][4];
        #pragma unroll
        for (int i = 0; i < 4; ++i)
            #pragma unroll
            for (int j = 0; j < 4; ++j) accd[i][j] = 0.0;

        for (int dc = 0; dc < NDC; ++dc) {
            const int p = kt * NDC + dc;
            float* buf = eT[p & 1];
            __syncthreads();                 // readers of this buffer (p-2) done
            *(float4*)(buf + cid0 * 4) = sA; // linear ds_write_b128
            *(float4*)(buf + cid1 * 4) = sB;
            __syncthreads();                 // buf visible to all

            // prefetch next phase AFTER the barrier: the implicit vmcnt
            // drain before the NEXT phase's barrier is a full compute later
            if (p + 1 < NPH) {
                const int nk0 = ((p + 1) >> 3) * TK;
                const int nd0 = ((p + 1) & 7) * DB;
                const float* src = cb + nk0 * DIM + nd0;
                sA = *(const float4*)(src + gof0);
                sB = *(const float4*)(src + gof1);
            }

            const float* zp = x + xbase + (size_t)(dc * DB) * HW + tm4;
            float af[4][4];

            // ---- q = 0 (d = 0..3): start the fp32 chains with a mul ----
            {
                float4 e0 = *(const float4*)(buf + sb0);
                float4 e1 = *(const float4*)(buf + sb1);
                float4 e2 = *(const float4*)(buf + sb2);
                float4 e3 = *(const float4*)(buf + sb3);
                #pragma unroll
                for (int dd = 0; dd < 4; ++dd) {
                    float4 zv = *(const float4*)(zp + (size_t)dd * HW);
                    float za[4] = {zv.x, zv.y, zv.z, zv.w};
                    float ea[4] = {((const float*)&e0)[dd], ((const float*)&e1)[dd],
                                   ((const float*)&e2)[dd], ((const float*)&e3)[dd]};
                    #pragma unroll
                    for (int i = 0; i < 4; ++i)
                        #pragma unroll
                        for (int j = 0; j < 4; ++j)
                            af[i][j] = (dd == 0) ? __fmul_rn(za[i], ea[j])   // fma(a,b,0)==a*b
                                                 : fmaf(za[i], ea[j], af[i][j]);
                }
            }
            // ---- q = 1..7: pure fma, d ascending ----
            #pragma unroll 2
            for (int q = 1; q < 8; ++q) {
                const int qo = q << 2;       // bq<<2, XORed into swizzled base
                float4 e0 = *(const float4*)(buf + (sb0 ^ qo));
                float4 e1 = *(const float4*)(buf + (sb1 ^ qo));
                float4 e2 = *(const float4*)(buf + (sb2 ^ qo));
                float4 e3 = *(const float4*)(buf + (sb3 ^ qo));
                const float* zq = zp + (size_t)qo * HW;
                #pragma unroll
                for (int dd = 0; dd < 4; ++dd) {
                    float4 zv = *(const float4*)(zq + (size_t)dd * HW);
                    float za[4] = {zv.x, zv.y, zv.z, zv.w};
                    float ea[4] = {((const float*)&e0)[dd], ((const float*)&e1)[dd],
                                   ((const float*)&e2)[dd], ((const float*)&e3)[dd]};
                    #pragma unroll
                    for (int i = 0; i < 4; ++i)
                        #pragma unroll
                        for (int j = 0; j < 4; ++j)
                            af[i][j] = fmaf(za[i], ea[j], af[i][j]);
                }
            }
            #pragma unroll
            for (int i = 0; i < 4; ++i)
                #pragma unroll
                for (int j = 0; j < 4; ++j) accd[i][j] += (double)af[i][j];
        }

        // ---- replicate numpy: d = fl32( fl32(T_n + U_k) - 2*fl32(dot) ) ----
        float4 uv = *(const float4*)(u2 + k0 + tk4);
        float ua[4] = {uv.x, uv.y, uv.z, uv.w};
        #pragma unroll
        for (int j = 0; j < 4; ++j) {
            const int kk = k0 + tk4 + j;
            #pragma unroll
            for (int i = 0; i < 4; ++i) {
                float m32 = (float)accd[i][j];              // fl32(dot)
                float c   = __fmul_rn(2.0f, m32);           // exact
                float t1  = __fadd_rn(Tsr[i], ua[j]);       // fl32(T+U)
                float d32 = __fsub_rn(t1, c);               // fl32(t1-c)
                // strict < keeps the earliest k (ks ascend within a thread)
                if (d32 < best_v[i]) { best_v[i] = d32; best_k[i] = kk; }
            }
        }
    }

    // ---- argmin reduction across the 4 tk-subgroups within the wave ----
    #pragma unroll
    for (int i = 0; i < 4; ++i) {
        float v = best_v[i]; int k = best_k[i];
        #pragma unroll
        for (int off = 16; off < 64; off <<= 1) {
            float ov = __shfl_xor(v, off, 64);
            int   ok = __shfl_xor(k, off, 64);
            if (ov < v || (ov == v && ok < k)) { v = ov; k = ok; }
        }
        best_v[i] = v; best_k[i] = k;
    }
    const int wv = t >> 6;              // wave id 0..3
    if ((t & 63) < 16) {
        #pragma unroll
        for (int i = 0; i < 4; ++i) {
            red_v[wv][tm4 + i] = best_v[i];
            red_k[wv][tm4 + i] = best_k[i];
        }
    }
    __syncthreads();
    if (t < TM) {
        float bv = red_v[0][t]; int bk = red_k[0][t];
        #pragma unroll
        for (int q = 1; q < 4; ++q) {
            float v = red_v[q][t]; int k = red_k[q][t];
            if (v < bv || (v == bv && k < bk)) { bv = v; bk = k; }
        }
        bestk_s[t] = bk;
        out[IDX_OFF + n0 + t] = (float)bk;   // indices as float
    }
    __syncthreads();

    // ---- epilogue: quantized output + fused loss (x re-read from global) ----
    float lsum = 0.f;
    {
        const int m = t & 63;
        const int kq = bestk_s[m];
        const float* crow = cb + (size_t)kq * DIM;
        for (int c = (t >> 6); c < DIM; c += 4) {
            float qv = crow[c];
            float xv = x[xbase + (size_t)c * HW + m];
            float d  = qv - xv;
            lsum = fmaf(d, d, lsum);
            out[xbase + (size_t)c * HW + m] = qv;
        }
    }
    #pragma unroll
    for (int off = 32; off > 0; off >>= 1) lsum += __shfl_down(lsum, off, 64);
    if ((t & 63) == 0) wsum[wv] = lsum;
    __syncthreads();
    if (t == 0) {
        float s = (wsum[0] + wsum[1]) + (wsum[2] + wsum[3]);
        // vq_loss = q_latent + 0.25*e_latent, both equal mean((q-x)^2)
        atomicAdd(out + LOSS_OFF, s * (1.25f / 8388608.0f));
    }
}

extern "C" void kernel_launch(void* const* d_in, const int* in_sizes, int n_in,
                              void* d_out, int out_size, void* d_ws, size_t ws_size,
                              hipStream_t stream) {
    const float* x  = (const float*)d_in[0];
    const float* cb = (const float*)d_in[1];
    float* out = (float*)d_out;
    float* u2  = (float*)d_ws;          // 4 KB scratch (numpy-order ||e||^2)

    // zero the loss slot (atomicAdd target); graph-capture-safe
    hipMemsetAsync(out + LOSS_OFF, 0, sizeof(float), stream);
    u2_kernel<<<NUM_K / 256, 256, 0, stream>>>(cb, u2);
    vq_main<<<N_TOT / TM, 256, 0, stream>>>(x, cb, u2, out);
}

// Round 4
// 485.487 us; speedup vs baseline: 1.1810x; 1.1810x over previous
//
#include <hip/hip_runtime.h>

// VectorQuantizer on MI355X — replicate numpy-fp32 rounding in the distance,
// so argmin matches the np reference's grid-quantized distances exactly.
// x: (32,256,32,32) fp32, codebook: (1024,256) fp32.
// Outputs concat: quantized (8388608 f32), vq_loss (1 f32), indices (32768 as f32).
//
// v5: lane=m layout; z read ONCE into registers; e via the SCALAR pipe.
// v1-v3 were LDS-instruction-bound (both operands from LDS); v4 moved z to
// VMEM but re-read the x-tile 16x -> L2 thrash (FETCH 170MB), latency-bound.
// Here: block = 512 threads = 8 waves; lane = m (64 rows), wave w owns
// d-chunk [32w, 32w+32) — exactly one numpy 32-chunk.
//  - z[32] per lane in VGPRs, loaded once (coalesced). x fetched once/block.
//  - e[k][d] is wave-uniform (k,d uniform; wave id readfirstlane'd) ->
//    compiler emits s_load into SGPRs; v_fma with SGPR operand. No LDS, no
//    VMEM in the GEMM inner loop.
//  - per k-group (16 k's): each wave writes af(m,k,chunk=w) to a 16KB
//    XOR-swizzled LDS buffer (2-way banks = free); combine phase sums the
//    8 chunks in ASCENDING order in double (exact), rounds once to f32 —
//    bit-identical to v1's accd[...] += (double)af per-dc accumulation.
//  - d32 = fl32( fl32(T+U) - 2*fl32(dot) ), strict < earliest-k: unchanged.

#define NUM_K 1024
#define DIM   256
#define HW    1024          // H*W
#define N_TOT 32768         // B*H*W
#define TM    64            // rows per block (= lanes)
#define KG    16            // k's per group
#define NG    (NUM_K / KG)  // 64 groups
#define DW    32            // d's per wave (= numpy chunk)
#define LOSS_OFF 8388608
#define IDX_OFF  8388609

// numpy pairwise sum of squares over 256 elements, exact numpy order.
__device__ __forceinline__ float np_sumsq_256(const float* p, int stride) {
    float s[2];
    #pragma unroll
    for (int h = 0; h < 2; ++h) {
        const float* base = p + h * 128 * stride;
        float r[8];
        #pragma unroll
        for (int j = 0; j < 8; ++j) {
            float v = base[j * stride];
            r[j] = __fmul_rn(v, v);
        }
        for (int i = 8; i < 128; i += 8) {
            #pragma unroll
            for (int j = 0; j < 8; ++j) {
                float v = base[(i + j) * stride];
                r[j] = __fadd_rn(r[j], __fmul_rn(v, v));
            }
        }
        s[h] = __fadd_rn(__fadd_rn(__fadd_rn(r[0], r[1]), __fadd_rn(r[2], r[3])),
                         __fadd_rn(__fadd_rn(r[4], r[5]), __fadd_rn(r[6], r[7])));
    }
    return __fadd_rn(s[0], s[1]);
}

__global__ __launch_bounds__(256) void u2_kernel(const float* __restrict__ cb,
                                                 float* __restrict__ u2) {
    int k = blockIdx.x * 256 + threadIdx.x;     // 4 blocks x 256
    u2[k] = np_sumsq_256(cb + (size_t)k * DIM, 1);
}

__global__ __launch_bounds__(512) void vq_main(const float* __restrict__ x,
                                               const float* __restrict__ cb,
                                               const float* __restrict__ u2,
                                               float* __restrict__ out) {
    // af_lds[k][m][c]: 16*64*8 words = 16 KB; c is XOR-swizzled by
    // (m&7)^((m>>3)&7) -> all writes/reads are <=2-way bank = free.
    __shared__ float af_lds[KG * TM * 8];
    __shared__ float Ts_s[TM];
    __shared__ int   bestk_s[TM];
    __shared__ float wsum[8];
    // final-reduction arrays alias af_lds (barrier-separated):
    float* red_v = af_lds;                    // [16][64]
    int*   red_k = (int*)(af_lds + 1024);     // [16][64]

    const int t    = threadIdx.x;
    const int lane = t & 63;                  // = m for z/epilogue
    const int wid_ = t >> 6;                  // wave id 0..7 (lane-varying view)
    const int wid  = __builtin_amdgcn_readfirstlane(wid_);   // uniform view
    const int d0   = wid * DW;                // this wave's d-chunk base

    const int g  = blockIdx.x;                // 512 blocks
    const int n0 = g * TM;
    const int b  = n0 >> 10;                  // /1024
    const int r0 = n0 & (HW - 1);
    const size_t xbase = (size_t)b * (DIM * HW) + r0;

    // ---- z: this wave's 32-d slice for this lane's m — loaded ONCE ----
    float z[DW];
    #pragma unroll
    for (int dd = 0; dd < DW; ++dd)
        z[dd] = x[xbase + (size_t)(d0 + dd) * HW + lane];

    // ---- numpy-order ||z||^2 per m (wave 0; coalesced per-d loads) ----
    if (wid_ == 0) Ts_s[lane] = np_sumsq_256(x + xbase + lane, HW);
    __syncthreads();

    // ---- per-thread combine constants: pairs (mA,kk),(mA+1,kk) ----
    const int mA    = (2 * t) & 63;           // even; mB = mA+1
    const int strip = t >> 5;                 // 0..15: k within group
    const float tsA = Ts_s[mA];
    const float tsB = Ts_s[mA + 1];
    const int permA = (mA & 7) ^ ((mA >> 3) & 7);
    const int permB = ((mA + 1) & 7) ^ (((mA + 1) >> 3) & 7);
    const int rbA   = (strip << 9) + (mA << 3);        // read bases
    const int rbB   = (strip << 9) + ((mA + 1) << 3);
    // write slot for this wave's chunk: swizzled by lane's perm
    const int wbase = (lane << 3) + (wid_ ^ (lane & 7) ^ ((lane >> 3) & 7));

    float bvA = 3.4e38f, bvB = 3.4e38f;
    int   bkA = 0,       bkB = 0;

    for (int gg = 0; gg < NG; ++gg) {
        // issue u2 for this group's k early (used after the barrier)
        const float u2v = u2[gg * KG + strip];

        // ---- compute: af(m, k, chunk=wid) for 16 k's; e via s_load ----
        const float* ebase = cb + (size_t)gg * KG * DIM + d0;   // uniform
        #pragma unroll
        for (int kk = 0; kk < KG; ++kk) {
            const float* er = ebase + kk * DIM;                 // uniform row
            float af = __fmul_rn(z[0], er[0]);                  // chain start
            #pragma unroll
            for (int dd = 1; dd < DW; ++dd)
                af = fmaf(z[dd], er[dd], af);                   // ascending d
            af_lds[(kk << 9) + wbase] = af;
        }
        __syncthreads();

        // ---- combine: sum 8 chunks ascending in double, round once ----
        {
            double accA = 0.0, accB = 0.0;
            #pragma unroll
            for (int c = 0; c < 8; ++c) {
                accA += (double)af_lds[rbA + (c ^ permA)];
                accB += (double)af_lds[rbB + (c ^ permB)];
            }
            const int kglob = gg * KG + strip;
            float m32, c2, t1, d32;
            m32 = (float)accA;                       // fl32(dot)
            c2  = __fmul_rn(2.0f, m32);              // exact
            t1  = __fadd_rn(tsA, u2v);               // fl32(T+U)
            d32 = __fsub_rn(t1, c2);                 // fl32(t1-c)
            if (d32 < bvA) { bvA = d32; bkA = kglob; }   // earliest-k tie-break
            m32 = (float)accB;
            c2  = __fmul_rn(2.0f, m32);
            t1  = __fadd_rn(tsB, u2v);
            d32 = __fsub_rn(t1, c2);
            if (d32 < bvB) { bvB = d32; bkB = kglob; }
        }
        __syncthreads();   // af_lds reusable next group
    }

    // ---- final per-m argmin across the 16 k-strips (red aliases af_lds) ----
    red_v[strip * TM + mA]     = bvA;  red_k[strip * TM + mA]     = bkA;
    red_v[strip * TM + mA + 1] = bvB;  red_k[strip * TM + mA + 1] = bkB;
    __syncthreads();
    if (t < TM) {
        float bv = red_v[t]; int bk = red_k[t];
        #pragma unroll
        for (int s = 1; s < 16; ++s) {
            float v = red_v[s * TM + t]; int k = red_k[s * TM + t];
            if (v < bv || (v == bv && k < bk)) { bv = v; bk = k; }
        }
        bestk_s[t] = bk;
        out[IDX_OFF + n0 + t] = (float)bk;   // indices as float
    }
    __syncthreads();

    // ---- epilogue: quantized output + fused loss (x re-read, L2/L3-hot) ----
    float lsum = 0.f;
    {
        const int m = t & 63;
        const int kq = bestk_s[m];
        const float* crow = cb + (size_t)kq * DIM;
        for (int c = (t >> 6); c < DIM; c += 8) {
            float qv = crow[c];
            float xv = x[xbase + (size_t)c * HW + m];
            float d  = qv - xv;
            lsum = fmaf(d, d, lsum);
            out[xbase + (size_t)c * HW + m] = qv;
        }
    }
    #pragma unroll
    for (int off = 32; off > 0; off >>= 1) lsum += __shfl_down(lsum, off, 64);
    if ((t & 63) == 0) wsum[wid_] = lsum;
    __syncthreads();
    if (t == 0) {
        float s = __fadd_rn(__fadd_rn(__fadd_rn(wsum[0], wsum[1]),
                                      __fadd_rn(wsum[2], wsum[3])),
                            __fadd_rn(__fadd_rn(wsum[4], wsum[5]),
                                      __fadd_rn(wsum[6], wsum[7])));
        // vq_loss = q_latent + 0.25*e_latent, both equal mean((q-x)^2)
        atomicAdd(out + LOSS_OFF, s * (1.25f / 8388608.0f));
    }
}

extern "C" void kernel_launch(void* const* d_in, const int* in_sizes, int n_in,
                              void* d_out, int out_size, void* d_ws, size_t ws_size,
                              hipStream_t stream) {
    const float* x  = (const float*)d_in[0];
    const float* cb = (const float*)d_in[1];
    float* out = (float*)d_out;
    float* u2  = (float*)d_ws;          // 4 KB scratch (numpy-order ||e||^2)

    // zero the loss slot (atomicAdd target); graph-capture-safe
    hipMemsetAsync(out + LOSS_OFF, 0, sizeof(float), stream);
    u2_kernel<<<NUM_K / 256, 256, 0, stream>>>(cb, u2);
    vq_main<<<N_TOT / TM, 512, 0, stream>>>(x, cb, u2, out);
}